// Round 8
// baseline (323.538 us; speedup 1.0000x reference)
//
#include <hip/hip_runtime.h>
#include <hip/hip_bf16.h>
#include <math.h>

#define SB 8     // batch
#define SS 1024  // N == M
#define SDM 512  // model dim
#define SH 8     // heads
#define SD 64    // head dim

typedef unsigned short ushort;
typedef __attribute__((ext_vector_type(8))) short bf16x8;
typedef __attribute__((ext_vector_type(4))) float f32x4;

#define MFMA16(a, b, c) __builtin_amdgcn_mfma_f32_16x16x32_bf16(a, b, c, 0, 0, 0)

static __device__ __forceinline__ ushort f2b(float f) {
    union { float f; unsigned u; } v; v.f = f;
    unsigned r = v.u + 0x7FFF + ((v.u >> 16) & 1);   // round-nearest-even
    return (ushort)(r >> 16);
}
static __device__ __forceinline__ float b2f(ushort u) {
    union { unsigned u; float f; } v; v.u = (unsigned)u << 16; return v.f;
}

// async global->LDS, 16 bytes per lane (dest = wave-uniform base + lane*16)
static __device__ __forceinline__ void gll16(const void* g, void* l) {
    __builtin_amdgcn_global_load_lds(
        (const __attribute__((address_space(1))) unsigned int*)g,
        (__attribute__((address_space(3))) unsigned int*)l, 16, 0, 0);
}

// ---------------------------------------------------------------------------
// Weight convert via LDS transpose -> bf16 Wt[which][col][k], coalesced both
// sides. grid 320: id<256 -> {q,k,v,p}_kernel [H,DM,D]; else projection [DM,DM].
// ---------------------------------------------------------------------------
__global__ __launch_bounds__(256) void convert_w_kernel(
    const float* __restrict__ qw, const float* __restrict__ kw,
    const float* __restrict__ vw, const float* __restrict__ pw,
    const float* __restrict__ projw, ushort* __restrict__ wt)
{
    __shared__ ushort T[64][72];
    const int id = blockIdx.x;
    const int tid = threadIdx.x;

    if (id < 256) {
        const int which = id >> 6, h = (id >> 3) & 7, kt = id & 7;
        const float* W = (which == 0) ? qw : (which == 1) ? kw
                       : (which == 2) ? vw : pw;
        const int kk = tid >> 2, d4 = (tid & 3) * 16;
        const float* src = W + ((size_t)h * SDM + kt * 64 + kk) * SD + d4;
#pragma unroll
        for (int j = 0; j < 4; ++j) {
            float4 v = *(const float4*)(src + j * 4);
            T[kk][d4 + j * 4 + 0] = f2b(v.x); T[kk][d4 + j * 4 + 1] = f2b(v.y);
            T[kk][d4 + j * 4 + 2] = f2b(v.z); T[kk][d4 + j * 4 + 3] = f2b(v.w);
        }
        __syncthreads();
        const int d = tid >> 2, kseg = (tid & 3) * 16;
        union { ushort u[16]; uint4 v4[2]; } o;
#pragma unroll
        for (int j = 0; j < 16; ++j) o.u[j] = T[kseg + j][d];
        uint4* dst = (uint4*)&wt[((size_t)which * SDM + h * 64 + d) * SDM + kt * 64 + kseg];
        dst[0] = o.v4[0]; dst[1] = o.v4[1];
    } else {
        const int id2 = id - 256, kt = id2 >> 3, ct = id2 & 7;
        const int kk = tid >> 2, c4 = (tid & 3) * 16;
        const float* src = projw + ((size_t)(kt * 64 + kk)) * SDM + ct * 64 + c4;
#pragma unroll
        for (int j = 0; j < 4; ++j) {
            float4 v = *(const float4*)(src + j * 4);
            T[kk][c4 + j * 4 + 0] = f2b(v.x); T[kk][c4 + j * 4 + 1] = f2b(v.y);
            T[kk][c4 + j * 4 + 2] = f2b(v.z); T[kk][c4 + j * 4 + 3] = f2b(v.w);
        }
        __syncthreads();
        const int c = tid >> 2, kseg = (tid & 3) * 16;
        union { ushort u[16]; uint4 v4[2]; } o;
#pragma unroll
        for (int j = 0; j < 16; ++j) o.u[j] = T[kseg + j][c];
        uint4* dst = (uint4*)&wt[(size_t)4 * SDM * SDM
                                 + ((size_t)(ct * 64 + c)) * SDM + kt * 64 + kseg];
        dst[0] = o.v4[0]; dst[1] = o.v4[1];
    }
}

// ---------------------------------------------------------------------------
// Kernel 1: bf16 MFMA projection GEMM, 128x128 tile. A staged DIRECTLY from
// fp32 inputs (inline f2b -> ds_write, padded stride 40 vs bank aliasing);
// B staged via global_load_lds from bf16 wt. Coalesced LDS epilogue.
// Linear grid 1024, XCD-swizzled so the 4 col-tiles sharing an A-panel land
// on the same XCD L2. q_u/q_v pre-scaled by 1/sqrt(D); v chunk-tiled.
// ---------------------------------------------------------------------------
__global__ __launch_bounds__(256) void projmm_kernel(
    const float* __restrict__ xq, const float* __restrict__ xk,
    const float* __restrict__ xv, const float* __restrict__ xp,
    const ushort* __restrict__ wt,
    const float* __restrict__ bias_u, const float* __restrict__ bias_v,
    ushort* __restrict__ quo, ushort* __restrict__ qvo,
    ushort* __restrict__ ko, ushort* __restrict__ po,
    ushort* __restrict__ vto)
{
    __shared__ ushort Asm[128 * 40];   // 10 KB, padded stride
    __shared__ ushort Bsm[128 * 32];   //  8 KB
    __shared__ ushort Ct[128][136];    // 34 KB epilogue staging

    const int tid  = threadIdx.x;
    const int wave = tid >> 6, lane = tid & 63;
    const int quad = lane >> 4, l15 = lane & 15;

    const int id  = blockIdx.x;
    const int xcd = id & 7;
    const int s   = id >> 3;            // 0..127
    const int which = s >> 5;
    const int s5  = s & 31;
    const int row0 = (xcd * 8 + (s5 >> 2)) * 128;
    const int col0 = (s5 & 3) * 128;
    const int wr = wave >> 1, wc = wave & 1;

    const float* X = (which == 0) ? xq : (which == 1) ? xk : (which == 2) ? xv : xp;
    const float* A  = X + (size_t)row0 * SDM;
    const ushort* Bw = wt + (size_t)which * (SDM * SDM) + (size_t)col0 * SDM;

    f32x4 acc[4][4];
#pragma unroll
    for (int i = 0; i < 4; ++i)
#pragma unroll
        for (int j = 0; j < 4; ++j) acc[i][j] = (f32x4){0.f, 0.f, 0.f, 0.f};

    const int ar = tid >> 1;            // A staging: row 0..127
    const int ah = (tid & 1) * 16;      // 16-elem half

    for (int k0 = 0; k0 < SDM; k0 += 32) {
#pragma unroll
        for (int j = 0; j < 2; ++j) {
            int t = j * 256 + tid;
            int r = t >> 2, kp = (t & 3) * 8;
            gll16(Bw + (size_t)r * SDM + k0 + kp, (char*)Bsm + t * 16);
        }
        {
            const float* ap = A + (size_t)ar * SDM + k0 + ah;
            union { ushort u[16]; uint4 v4[2]; } o;
#pragma unroll
            for (int j = 0; j < 4; ++j) {
                float4 v = *(const float4*)(ap + j * 4);
                o.u[j * 4 + 0] = f2b(v.x); o.u[j * 4 + 1] = f2b(v.y);
                o.u[j * 4 + 2] = f2b(v.z); o.u[j * 4 + 3] = f2b(v.w);
            }
            uint4* dst = (uint4*)&Asm[ar * 40 + ah];
            dst[0] = o.v4[0]; dst[1] = o.v4[1];
        }
        __syncthreads();

        bf16x8 af[4], bfr[4];
#pragma unroll
        for (int mt = 0; mt < 4; ++mt)
            af[mt] = *(const bf16x8*)&Asm[(wr * 64 + mt * 16 + l15) * 40 + quad * 8];
#pragma unroll
        for (int nt = 0; nt < 4; ++nt)
            bfr[nt] = *(const bf16x8*)&Bsm[(wc * 64 + nt * 16 + l15) * 32 + quad * 8];
#pragma unroll
        for (int mt = 0; mt < 4; ++mt)
#pragma unroll
            for (int nt = 0; nt < 4; ++nt)
                acc[mt][nt] = MFMA16(af[mt], bfr[nt], acc[mt][nt]);
        __syncthreads();
    }

    const float SC = 0.125f;   // 1/sqrt(D) folded into q
    const int strow = tid >> 1;
    const int sthalf = tid & 1;

    if (which == 0) {
#pragma unroll
        for (int nt = 0; nt < 4; ++nt) {
            const int lc = wc * 64 + nt * 16 + l15;
            const float bu = bias_u[col0 + lc];
#pragma unroll
            for (int mt = 0; mt < 4; ++mt) {
                const int lr = wr * 64 + mt * 16 + quad * 4;
#pragma unroll
                for (int r = 0; r < 4; ++r)
                    Ct[lr + r][lc] = f2b((acc[mt][nt][r] + bu) * SC);
            }
        }
        __syncthreads();
        {
            const int R = row0 + strow, b = R >> 10, n = R & 1023;
            const int C = col0 + sthalf * 64, h = C >> 6;
            uint4* dst = (uint4*)(quo + ((size_t)(b * SH + h) * SS + n) * SD);
            const uint4* src = (const uint4*)&Ct[strow][sthalf * 64];
#pragma unroll
            for (int j = 0; j < 8; ++j) dst[j] = src[j];
        }
        __syncthreads();
#pragma unroll
        for (int nt = 0; nt < 4; ++nt) {
            const int lc = wc * 64 + nt * 16 + l15;
            const float bv = bias_v[col0 + lc];
#pragma unroll
            for (int mt = 0; mt < 4; ++mt) {
                const int lr = wr * 64 + mt * 16 + quad * 4;
#pragma unroll
                for (int r = 0; r < 4; ++r)
                    Ct[lr + r][lc] = f2b((acc[mt][nt][r] + bv) * SC);
            }
        }
        __syncthreads();
        {
            const int R = row0 + strow, b = R >> 10, n = R & 1023;
            const int C = col0 + sthalf * 64, h = C >> 6;
            uint4* dst = (uint4*)(qvo + ((size_t)(b * SH + h) * SS + n) * SD);
            const uint4* src = (const uint4*)&Ct[strow][sthalf * 64];
#pragma unroll
            for (int j = 0; j < 8; ++j) dst[j] = src[j];
        }
    } else if (which == 1 || which == 3) {
#pragma unroll
        for (int nt = 0; nt < 4; ++nt) {
            const int lc = wc * 64 + nt * 16 + l15;
#pragma unroll
            for (int mt = 0; mt < 4; ++mt) {
                const int lr = wr * 64 + mt * 16 + quad * 4;
#pragma unroll
                for (int r = 0; r < 4; ++r)
                    Ct[lr + r][lc] = f2b(acc[mt][nt][r]);
            }
        }
        __syncthreads();
        {
            ushort* out = (which == 1) ? ko : po;
            const int R = row0 + strow, b = R >> 10, n = R & 1023;
            const int C = col0 + sthalf * 64, h = C >> 6;
            uint4* dst = (uint4*)(out + ((size_t)(b * SH + h) * SS + n) * SD);
            const uint4* src = (const uint4*)&Ct[strow][sthalf * 64];
#pragma unroll
            for (int j = 0; j < 8; ++j) dst[j] = src[j];
        }
    } else {
        // v: transpose in Ct so the store is row-coalesced into chunk-tiled vto
#pragma unroll
        for (int nt = 0; nt < 4; ++nt) {
            const int lc = wc * 64 + nt * 16 + l15;
#pragma unroll
            for (int mt = 0; mt < 4; ++mt) {
                const int lr = wr * 64 + mt * 16 + quad * 4;
#pragma unroll
                for (int r = 0; r < 4; ++r)
                    Ct[lc][lr + r] = f2b(acc[mt][nt][r]);
            }
        }
        __syncthreads();
        {
            const int C = col0 + strow, h = C >> 6, d = C & 63;
            const int b = row0 >> 10;
            const int nloc = (row0 & 1023) + sthalf * 64;
            uint4* dst = (uint4*)(vto + (size_t)(b * SH + h) * SS * SD
                                  + ((size_t)((nloc >> 6) * 64 + d)) * 64);
            const uint4* src = (const uint4*)&Ct[strow][sthalf * 64];
#pragma unroll
            for (int j = 0; j < 8; ++j) dst[j] = src[j];
        }
    }
}

// XOR-swizzled LDS fragment read (16B seg of 128B row)
static __device__ __forceinline__ bf16x8 sfrag(const ushort* buf, int row, int seg) {
    return *(const bf16x8*)&buf[(size_t)row * 64 + ((seg ^ (row & 7)) * 8)];
}

// ---------------------------------------------------------------------------
// Kernel 2: bf16 MFMA attention, SPLIT-K: each block does 8 of 16 m-chunks,
// writes unnormalized O (bf16) + row-sum l to partial buffers; combine kernel
// merges. Single-buffer k/p LDS staging (44 KB -> 3 blocks/CU), P-scratch
// aliased on gather scratch. grid 2048, XCD-clustered. No online max.
// ---------------------------------------------------------------------------
__global__ __launch_bounds__(256) void attn_kernel(
    const ushort* __restrict__ qu, const ushort* __restrict__ qv,
    const ushort* __restrict__ kk, const ushort* __restrict__ pp,
    const ushort* __restrict__ vt,
    ushort* __restrict__ Op0, ushort* __restrict__ Op1,
    float* __restrict__ l0, float* __restrict__ l1)
{
    __shared__ ushort Kb[64 * 64];       //  8 KB
    __shared__ ushort Pb[128 * 64];      // 16 KB
    __shared__ float  Glds[4][16][80];   // 20 KB (P-scratch aliased)

    const int tid  = threadIdx.x;
    const int wave = tid >> 6;
    const int lane = tid & 63;
    const int quad = lane >> 4;
    const int l15  = lane & 15;

    const int id   = blockIdx.x;
    const int xcd  = id & 7;
    const int slot = id >> 3;                 // 0..255
    const int bhid = xcd * 8 + (slot >> 5);   // 0..63
    const int r5   = slot & 31;
    const int half = r5 >> 4;
    const int nt   = r5 & 15;
    const int b    = bhid >> 3;
    const int h    = bhid & 7;
    const int n0   = nt * 64;
    const int mc0  = half * 8;

    const size_t bh   = (size_t)(b * SH + h);
    const ushort* qu_bh = qu + bh * SS * SD;
    const ushort* qv_bh = qv + bh * SS * SD;
    const ushort* k_bh  = kk + bh * SS * SD;
    const ushort* p_bh  = pp + bh * SS * SD;
    const ushort* vt_bh = vt + bh * SS * SD;   // chunk-tiled [mc][d][64]

    const int mcD = n0 >> 6;

    const int arow  = n0 + wave * 16 + l15;
    const int arow2 = (arow + 1 < SS) ? arow + 1 : SS - 1;

    bf16x8 a_u0  = *(const bf16x8*)(qu_bh + (size_t)arow  * SD + quad * 8);
    bf16x8 a_u1  = *(const bf16x8*)(qu_bh + (size_t)arow  * SD + quad * 8 + 32);
    bf16x8 a_vl0 = *(const bf16x8*)(qv_bh + (size_t)arow  * SD + quad * 8);
    bf16x8 a_vl1 = *(const bf16x8*)(qv_bh + (size_t)arow  * SD + quad * 8 + 32);
    bf16x8 a_vu0 = *(const bf16x8*)(qv_bh + (size_t)arow2 * SD + quad * 8);
    bf16x8 a_vu1 = *(const bf16x8*)(qv_bh + (size_t)arow2 * SD + quad * 8 + 32);

    float lsum[4] = {0.f, 0.f, 0.f, 0.f};
    f32x4 O[4];
#pragma unroll
    for (int dt = 0; dt < 4; ++dt) O[dt] = (f32x4){0.f, 0.f, 0.f, 0.f};

    float  (*Gl)[80] = Glds[wave];
    ushort (*Pl)[72] = (ushort (*)[72])Glds[wave];   // aliased, per-wave sequential

    auto stage = [&](int mc) {
        const int m0s = mc * 64;
        const int cb  = (mc <= mcD) ? (m0s - n0 + 960) : (m0s - n0 - 65);
#pragma unroll
        for (int it = 0; it < 2; ++it) {
            int t = it * 256 + tid;
            int r = t >> 3, s = t & 7;
            gll16(k_bh + (size_t)(m0s + r) * 64 + ((s ^ (r & 7)) * 8), (char*)Kb + t * 16);
        }
#pragma unroll
        for (int it = 0; it < 4; ++it) {
            int t = it * 256 + tid;
            int r = t >> 3, s = t & 7;
            int c = cb + r; c = (c < 0) ? 0 : (c > SS - 1 ? SS - 1 : c);
            gll16(p_bh + (size_t)c * 64 + ((s ^ (r & 7)) * 8), (char*)Pb + t * 16);
        }
    };

    stage(mc0);

    for (int mc = mc0; mc < mc0 + 8; ++mc) {
        const int m0 = mc * 64;
        const int diff = m0 - n0;
        const bool lowerband = (mc <= mcD);

        __syncthreads();   // staged data ready

        // v burst overlaps the S MFMAs below
        bf16x8 vb0[4], vb1[4];
#pragma unroll
        for (int dt = 0; dt < 4; ++dt) {
            const ushort* vp = vt_bh + (size_t)(m0 + dt * 16 + l15) * 64 + quad * 8;
            vb0[dt] = *(const bf16x8*)vp;
            vb1[dt] = *(const bf16x8*)(vp + 32);
        }

        f32x4 S[4];
#pragma unroll
        for (int mt = 0; mt < 4; ++mt) {
            const int r = mt * 16 + l15;
            f32x4 c = (f32x4){0.f, 0.f, 0.f, 0.f};
            c = MFMA16(a_u0, sfrag(Kb, r, quad), c);
            c = MFMA16(a_u1, sfrag(Kb, r, quad + 4), c);
            S[mt] = c;
        }

        float sv[4][4];
#pragma unroll
        for (int mt = 0; mt < 4; ++mt)
#pragma unroll
            for (int r = 0; r < 4; ++r) sv[mt][r] = 0.f;

        {
            const bf16x8 av0 = lowerband ? a_vl0 : a_vu0;
            const bf16x8 av1 = lowerband ? a_vl1 : a_vu1;
#pragma unroll
            for (int ti = 0; ti < 5; ++ti) {
                const int t = (3 - wave + ti) * 16 + l15;
                f32x4 g = (f32x4){0.f, 0.f, 0.f, 0.f};
                g = MFMA16(av0, sfrag(Pb, t, quad), g);
                g = MFMA16(av1, sfrag(Pb, t, quad + 4), g);
#pragma unroll
                for (int r = 0; r < 4; ++r)
                    Gl[quad * 4 + r][ti * 16 + l15] = g[r];
            }
#pragma unroll
            for (int mt = 0; mt < 4; ++mt) {
                const int mloc = mt * 16 + l15;
#pragma unroll
                for (int r = 0; r < 4; ++r) {
                    const int q4r = quad * 4 + r;
                    const int d1 = diff + mloc - (wave * 16 + q4r);
                    const bool use = lowerband ? (d1 <= 0) : (d1 >= 2);
                    if (use) sv[mt][r] = Gl[q4r][mloc - q4r + 15];
                }
            }
        }

        if (mc == mcD) {   // diagonal: upper band direct from global
            const int cbase = diff - 65;
            bf16x8 pu0[5], pu1[5];
#pragma unroll
            for (int ti = 0; ti < 5; ++ti) {
                int t = (3 - wave + ti) * 16 + l15;
                int c = cbase + t;
                c = (c < 0) ? 0 : (c > SS - 1 ? SS - 1 : c);
                const ushort* pr = p_bh + (size_t)c * SD + quad * 8;
                pu0[ti] = *(const bf16x8*)pr;
                pu1[ti] = *(const bf16x8*)(pr + 32);
            }
#pragma unroll
            for (int ti = 0; ti < 5; ++ti) {
                f32x4 g = (f32x4){0.f, 0.f, 0.f, 0.f};
                g = MFMA16(a_vu0, pu0[ti], g);
                g = MFMA16(a_vu1, pu1[ti], g);
#pragma unroll
                for (int r = 0; r < 4; ++r)
                    Gl[quad * 4 + r][ti * 16 + l15] = g[r];
            }
#pragma unroll
            for (int mt = 0; mt < 4; ++mt) {
                const int mloc = mt * 16 + l15;
#pragma unroll
                for (int r = 0; r < 4; ++r) {
                    const int q4r = quad * 4 + r;
                    const int d1 = diff + mloc - (wave * 16 + q4r);
                    if (d1 >= 2) sv[mt][r] = Gl[q4r][mloc - q4r + 15];
                }
            }
        }

        __syncthreads();                       // all waves done with Kb/Pb
        if (mc + 1 < mc0 + 8) stage(mc + 1);   // DMA overlaps exp/PV

        float e[4][4];
#pragma unroll
        for (int mt = 0; mt < 4; ++mt)
#pragma unroll
            for (int r = 0; r < 4; ++r) {
                e[mt][r] = __expf(S[mt][r] + sv[mt][r]);
                lsum[r] += e[mt][r];
            }

#pragma unroll
        for (int mt = 0; mt < 4; ++mt)
#pragma unroll
            for (int r = 0; r < 4; ++r)
                Pl[quad * 4 + r][mt * 16 + l15] = f2b(e[mt][r]);

        bf16x8 ap0 = *(const bf16x8*)&Pl[l15][quad * 8];
        bf16x8 ap1 = *(const bf16x8*)&Pl[l15][32 + quad * 8];
#pragma unroll
        for (int dt = 0; dt < 4; ++dt) {
            O[dt] = MFMA16(ap0, vb0[dt], O[dt]);
            O[dt] = MFMA16(ap1, vb1[dt], O[dt]);
        }
    }

#pragma unroll
    for (int mask = 1; mask <= 8; mask <<= 1)
#pragma unroll
        for (int r = 0; r < 4; ++r)
            lsum[r] += __shfl_xor(lsum[r], mask, 16);

    ushort* Op = half ? Op1 : Op0;
    float*  lp = half ? l1  : l0;

#pragma unroll
    for (int dt = 0; dt < 4; ++dt)
#pragma unroll
        for (int r = 0; r < 4; ++r) {
            int nn = n0 + wave * 16 + quad * 4 + r;
            Op[((size_t)b * SS + nn) * (SH * SD) + h * SD + dt * 16 + l15] =
                f2b(O[dt][r]);
        }
    if (l15 == 0) {
#pragma unroll
        for (int r = 0; r < 4; ++r) {
            int nn = n0 + wave * 16 + quad * 4 + r;
            lp[((size_t)b * SS + nn) * SH + h] = lsum[r];
        }
    }
}

// ---------------------------------------------------------------------------
// Combine split-K partials: ctx = (O0 + O1) / (l0 + l1). 8 elems/thread.
// ---------------------------------------------------------------------------
__global__ __launch_bounds__(256) void combine_kernel(
    const ushort* __restrict__ Op0, const ushort* __restrict__ Op1,
    const float* __restrict__ l0, const float* __restrict__ l1,
    ushort* __restrict__ ctx)
{
    const int gid = blockIdx.x * 256 + threadIdx.x;   // 524288 total
    const size_t E = (size_t)gid * 8;
    const int row = gid >> 6;                 // b*SS + n
    const int h   = (gid & 63) >> 3;
    const float inv = 1.f / (l0[(size_t)row * SH + h] + l1[(size_t)row * SH + h]);

    union { ushort u[8]; uint4 v4; } a, bo, o;
    a.v4  = *(const uint4*)(Op0 + E);
    bo.v4 = *(const uint4*)(Op1 + E);
#pragma unroll
    for (int j = 0; j < 8; ++j)
        o.u[j] = f2b((b2f(a.u[j]) + b2f(bo.u[j])) * inv);
    *(uint4*)(ctx + E) = o.v4;
}

// ---------------------------------------------------------------------------
// Kernel 3: output projection, bf16 MFMA GEMM.
// ---------------------------------------------------------------------------
__global__ __launch_bounds__(256) void outproj_kernel(
    const ushort* __restrict__ ctx, const ushort* __restrict__ wt,
    float* __restrict__ out)
{
    __shared__ ushort Asm[128 * 32];
    __shared__ ushort Bsm[128 * 32];

    const int tid  = threadIdx.x;
    const int wave = tid >> 6, lane = tid & 63;
    const int quad = lane >> 4, l15 = lane & 15;
    const int row0 = blockIdx.x * 128;
    const int col0 = blockIdx.y * 128;
    const int wr = wave >> 1, wc = wave & 1;

    const ushort* A  = ctx + (size_t)row0 * SDM;
    const ushort* Bw = wt + (size_t)4 * (SDM * SDM) + (size_t)col0 * SDM;

    f32x4 acc[4][4];
#pragma unroll
    for (int i = 0; i < 4; ++i)
#pragma unroll
        for (int j = 0; j < 4; ++j) acc[i][j] = (f32x4){0.f, 0.f, 0.f, 0.f};

    for (int k0 = 0; k0 < SDM; k0 += 32) {
#pragma unroll
        for (int j = 0; j < 2; ++j) {
            int t = j * 256 + tid;
            int r = t >> 2, kp = (t & 3) * 8;
            gll16(A  + (size_t)r * SDM + k0 + kp, (char*)Asm + t * 16);
            gll16(Bw + (size_t)r * SDM + k0 + kp, (char*)Bsm + t * 16);
        }
        __syncthreads();

        bf16x8 af[4], bfr[4];
#pragma unroll
        for (int mt = 0; mt < 4; ++mt)
            af[mt] = *(const bf16x8*)&Asm[(wr * 64 + mt * 16 + l15) * 32 + quad * 8];
#pragma unroll
        for (int nt = 0; nt < 4; ++nt)
            bfr[nt] = *(const bf16x8*)&Bsm[(wc * 64 + nt * 16 + l15) * 32 + quad * 8];
#pragma unroll
        for (int mt = 0; mt < 4; ++mt)
#pragma unroll
            for (int nt = 0; nt < 4; ++nt)
                acc[mt][nt] = MFMA16(af[mt], bfr[nt], acc[mt][nt]);
        __syncthreads();
    }

#pragma unroll
    for (int mt = 0; mt < 4; ++mt)
#pragma unroll
        for (int nt = 0; nt < 4; ++nt) {
            const int R = row0 + wr * 64 + mt * 16 + quad * 4;
            const int C = col0 + wc * 64 + nt * 16 + l15;
#pragma unroll
            for (int r = 0; r < 4; ++r)
                out[(size_t)(R + r) * SDM + C] = acc[mt][nt][r];
        }
}

// ---------------------------------------------------------------------------
extern "C" void kernel_launch(void* const* d_in, const int* in_sizes, int n_in,
                              void* d_out, int out_size, void* d_ws, size_t ws_size,
                              hipStream_t stream)
{
    const float* query  = (const float*)d_in[0];
    const float* key    = (const float*)d_in[1];
    const float* value  = (const float*)d_in[2];
    const float* pos    = (const float*)d_in[3];
    const float* qw     = (const float*)d_in[4];
    const float* kw     = (const float*)d_in[5];
    const float* vw     = (const float*)d_in[6];
    const float* pw     = (const float*)d_in[7];
    const float* projw  = (const float*)d_in[8];
    const float* bias_u = (const float*)d_in[9];
    const float* bias_v = (const float*)d_in[10];

    char* w = (char*)d_ws;
    const size_t MB = 1024 * 1024;
    ushort* quo = (ushort*)(w);               //  8 MB
    ushort* qvo = (ushort*)(w + 8 * MB);      //  8 MB
    ushort* ko  = (ushort*)(w + 16 * MB);     //  8 MB
    ushort* po  = (ushort*)(w + 24 * MB);     //  8 MB
    ushort* vto = (ushort*)(w + 32 * MB);     //  8 MB chunk-tiled [bh][mc][d][64]
    ushort* wt  = (ushort*)(w + 40 * MB);     // 2.5 MB (5 transposed weights)
    ushort* ctx = (ushort*)(w + 43 * MB);     //  8 MB
    ushort* Op0 = (ushort*)(w + 51 * MB);     //  8 MB bf16 partial O, half 0
    ushort* Op1 = (ushort*)(w + 59 * MB);     //  8 MB bf16 partial O, half 1
    float*  l0  = (float*)(w + 67 * MB);      // 256 KB partial l, half 0
    float*  l1  = (float*)(w + 67 * MB + 262144);

    convert_w_kernel<<<dim3(320), 256, 0, stream>>>(qw, kw, vw, pw, projw, wt);

    projmm_kernel<<<dim3(1024), 256, 0, stream>>>(query, key, value, pos, wt,
                                                  bias_u, bias_v,
                                                  quo, qvo, ko, po, vto);

    attn_kernel<<<dim3(2048), 256, 0, stream>>>(quo, qvo, ko, po, vto,
                                                Op0, Op1, l0, l1);

    combine_kernel<<<dim3(2048), 256, 0, stream>>>(Op0, Op1, l0, l1, ctx);

    dim3 g3(64, 4);
    outproj_kernel<<<g3, 256, 0, stream>>>(ctx, wt, (float*)d_out);
}